// Round 11
// baseline (11907.410 us; speedup 1.0000x reference)
//
#include <hip/hip_runtime.h>

#define TT 2048
#define BB 64
#define HH 256   // EMB == HID == 256

typedef _Float16 half8_t __attribute__((ext_vector_type(8)));
typedef float f32x4 __attribute__((ext_vector_type(4)));

// ---------------------------------------------------------------------------
// prep: transpose + fp16-convert W_ih and W_hh into [N][K] row-major. (~3 µs)
// ---------------------------------------------------------------------------
__global__ void prep_kernel(const float* __restrict__ Wih, const float* __restrict__ Whh,
                            _Float16* __restrict__ WihT, _Float16* __restrict__ WhhT) {
  const int n = blockIdx.x;   // output column
  const int k = threadIdx.x;  // input row
  WihT[n * HH + k] = (_Float16)Wih[k * HH + n];
  WhhT[n * HH + k] = (_Float16)Whh[k * HH + n];
}

// ---------------------------------------------------------------------------
// R20: fused producer/consumer kernel.
//   R19 post-mortem: embed micro-opts exhausted (876/905/880); scan frozen at
//   762. The ~114 µs non-scan is pure SERIALIZATION — scan consumes U[t] at
//   step t, so embed can run concurrently on the 192 CUs the scan leaves idle.
//   Blocks 0..63 = scan role (R15 body, math byte-identical). Blocks 64.. =
//   embed role (R9-verified fp32-emb body, one (t,ngroup) per block, low-t
//   first). Producer: U stores -> per-thread threadfence -> barrier -> tid0
//   release-add done[t]; completers advance prefix watermark wm (acquire
//   done-check + release CAS). Consumer: scan gates u-prefetch on cached
//   wm >= min(tc+16,TT); steady-state cost ~2 VALU / 8 steps.
//   Deadlock-impossible: scan <= 64 blocks => >=192 CUs always free for
//   embed; embed never waits on scan. done/wm re-zeroed per replay by
//   hipMemsetAsync (graph-capturable).
// ---------------------------------------------------------------------------
__global__ __launch_bounds__(256)
__attribute__((amdgpu_waves_per_eu(1, 1)))
void fused_kernel(const int* __restrict__ source, const float* __restrict__ emb,
                  const _Float16* __restrict__ WihT, const _Float16* __restrict__ WhhT,
                  const float* __restrict__ b_ih, const float* __restrict__ b_hh,
                  _Float16* __restrict__ U, float* __restrict__ out,
                  int* __restrict__ done, int* __restrict__ wmp) {
  __shared__ __align__(16) _Float16 Bs[64][280];   // embed role (36 KB)
  __shared__ __align__(16) _Float16 hbuf[2][HH];   // scan role (1 KB)
  const int tid = threadIdx.x;

  if (blockIdx.x >= BB) {
    // ================= embed role (R9-verified body) =================
    const int e = blockIdx.x - BB;
    const int t = e >> 2;              // ascending t => low t completes first
    const int nbase = (e & 3) * 64;

    for (int c = tid; c < 64 * 32; c += 256) {
      const int n = c >> 5;
      const int ko = (c & 31) * 8;
      *(half8_t*)&Bs[n][ko] = *(const half8_t*)(WihT + (size_t)(nbase + n) * HH + ko);
    }
    __syncthreads();

    const int lane = tid & 63;
    const int wave = tid >> 6;
    const int row16 = lane & 15;
    const int quad = lane >> 4;
    const int b = wave * 16 + row16;            // A-fragment row = batch
    const int src = source[b * TT + t];         // source is [B][T]
    const float* arow = emb + (size_t)src * HH + quad * 8;

    f32x4 acc[4];
#pragma unroll
    for (int ct = 0; ct < 4; ++ct) acc[ct] = (f32x4){0.f, 0.f, 0.f, 0.f};

#pragma unroll
    for (int kt = 0; kt < 8; ++kt) {
      const float4 x0 = *(const float4*)(arow + kt * 32);
      const float4 x1 = *(const float4*)(arow + kt * 32 + 4);
      half8_t af;
      af[0] = (_Float16)x0.x; af[1] = (_Float16)x0.y;
      af[2] = (_Float16)x0.z; af[3] = (_Float16)x0.w;
      af[4] = (_Float16)x1.x; af[5] = (_Float16)x1.y;
      af[6] = (_Float16)x1.z; af[7] = (_Float16)x1.w;
#pragma unroll
      for (int ct = 0; ct < 4; ++ct) {
        const half8_t bf = *(const half8_t*)&Bs[ct * 16 + row16][quad * 8 + kt * 32];
        acc[ct] = __builtin_amdgcn_mfma_f32_16x16x32_f16(af, bf, acc[ct], 0, 0, 0);
      }
    }

#pragma unroll
    for (int ct = 0; ct < 4; ++ct) {
      const int nn = nbase + ct * 16 + row16;   // C col = lane&15
      const float bias = b_ih[nn] + b_hh[nn];
#pragma unroll
      for (int r = 0; r < 4; ++r) {
        const int bb = wave * 16 + quad * 4 + r;  // C row = quad*4 + reg
        U[((size_t)t * BB + bb) * HH + nn] = (_Float16)(acc[ct][r] + bias);
      }
    }

    // ---- publish: U stores -> fence (per thread) -> barrier -> signal ----
    __threadfence();
    __syncthreads();
    if (tid == 0) {
      __hip_atomic_fetch_add(&done[t], 1, __ATOMIC_RELEASE, __HIP_MEMORY_SCOPE_AGENT);
      // advance prefix watermark while complete (done[w]==4)
      int w = __hip_atomic_load(wmp, __ATOMIC_RELAXED, __HIP_MEMORY_SCOPE_AGENT);
      while (w < TT &&
             __hip_atomic_load(&done[w], __ATOMIC_ACQUIRE, __HIP_MEMORY_SCOPE_AGENT) == 4) {
        int expct = w;
        if (__hip_atomic_compare_exchange_strong(wmp, &expct, w + 1, __ATOMIC_RELEASE,
                                                 __ATOMIC_RELAXED, __HIP_MEMORY_SCOPE_AGENT))
          w = w + 1;
        else
          w = expct;  // someone else advanced; re-check from there
      }
    }
    return;
  }

  // ================= scan role (R15 body, FROZEN math) =================
  const int b = blockIdx.x;
  const int w = tid >> 6;
  const int l = tid & 63;
  const int col = l & 15;    // n within tile
  const int quad = l >> 4;   // MFMA quad

  // wb[tt][j]: B-frag for n-tile 64w+16tt, k-chunk c=(2w+j)&7 (own chunks at
  // j=0,1). Lane reads WhhT[(64w+16tt+col)][32c + quad*8 .. +8].
  half8_t wb[4][8];
#pragma unroll
  for (int tt = 0; tt < 4; ++tt) {
    const _Float16* base = WhhT + (size_t)(64 * w + 16 * tt + col) * HH + quad * 8;
#pragma unroll
    for (int j = 0; j < 8; ++j) {
      const int c = (2 * w + j) & 7;
      wb[tt][j] = *(const half8_t*)(base + 32 * c);
    }
  }
  asm volatile("" : "+a"(wb[0][0]), "+a"(wb[0][1]), "+a"(wb[0][2]), "+a"(wb[0][3]),
                    "+a"(wb[0][4]), "+a"(wb[0][5]), "+a"(wb[0][6]), "+a"(wb[0][7]),
                    "+a"(wb[1][0]), "+a"(wb[1][1]), "+a"(wb[1][2]), "+a"(wb[1][3]),
                    "+a"(wb[1][4]), "+a"(wb[1][5]), "+a"(wb[1][6]), "+a"(wb[1][7]));
  asm volatile("" : "+a"(wb[2][0]), "+a"(wb[2][1]), "+a"(wb[2][2]), "+a"(wb[2][3]),
                    "+a"(wb[2][4]), "+a"(wb[2][5]), "+a"(wb[2][6]), "+a"(wb[2][7]),
                    "+a"(wb[3][0]), "+a"(wb[3][1]), "+a"(wb[3][2]), "+a"(wb[3][3]),
                    "+a"(wb[3][4]), "+a"(wb[3][5]), "+a"(wb[3][6]), "+a"(wb[3][7]));

  const int oO0 = 32 * ((2 * w + 0) & 7) + 8 * quad;  // own chunk j=0
  const int oO1 = 32 * ((2 * w + 1) & 7) + 8 * quad;  // own chunk j=1
  const int oX2 = 32 * ((2 * w + 2) & 7) + 8 * quad;
  const int oX3 = 32 * ((2 * w + 3) & 7) + 8 * quad;
  const int oX4 = 32 * ((2 * w + 4) & 7) + 8 * quad;
  const int oX5 = 32 * ((2 * w + 5) & 7) + 8 * quad;
  const int oX6 = 32 * ((2 * w + 6) & 7) + 8 * quad;
  const int oX7 = 32 * ((2 * w + 7) & 7) + 8 * quad;

  hbuf[0][tid] = (_Float16)0.f;  // h0 = 0

  // producer gate: cached watermark; acquire-load only when insufficient
  int ready = 0;
  long spin_budget = 1L << 26;   // bailout: avoid wedging the queue on a bug
  auto gate = [&](int need) {
    while (ready < need) {
      ready = __hip_atomic_load(wmp, __ATOMIC_ACQUIRE, __HIP_MEMORY_SCOPE_AGENT);
      if (ready >= need || --spin_budget < 0) break;
      __builtin_amdgcn_s_sleep(8);
    }
  };

  // Thread tid finalizes output n = tid: u stream is per-thread contiguous.
  const _Float16* Up = U + b * HH + tid;  // step stride = BB*HH halfs
  _Float16 uc[8], un[8];
  gate(8);
#pragma unroll
  for (int s = 0; s < 8; ++s) uc[s] = Up[(size_t)s * (BB * HH)];

  float hn = 0.f;
  f32x4 cacc[4];
#pragma unroll
  for (int tt = 0; tt < 4; ++tt) cacc[tt] = (f32x4){0.f, 0.f, 0.f, 0.f};

  // ---- prologue: own-chunk frags of h_0 + 8 pre-issued MFMAs (step 0) ----
  {
    half8_t hoA = *(const half8_t*)(hbuf[0] + oO0);
    half8_t hoB = *(const half8_t*)(hbuf[0] + oO1);
    asm volatile("" : "+v"(hoA), "+v"(hoB));
#pragma unroll
    for (int tt = 0; tt < 4; ++tt)
      cacc[tt] = __builtin_amdgcn_mfma_f32_16x16x32_f16(hoA, wb[tt][0], cacc[tt], 0, 0, 0);
#pragma unroll
    for (int tt = 0; tt < 4; ++tt)
      cacc[tt] = __builtin_amdgcn_mfma_f32_16x16x32_f16(hoB, wb[tt][1], cacc[tt], 0, 0, 0);
  }

  for (int tc = 0; tc < TT; tc += 8) {
    // Gate next-chunk u-loads on the producer watermark, then issue; raw
    // barriers never drain vmcnt, so they stay in flight 8 steps.
    const int tn = (tc + 8) & (TT - 1);
    {
      const int need = (tc + 16 < TT) ? (tc + 16) : TT;
      gate(need);
    }
#pragma unroll
    for (int s = 0; s < 8; ++s) un[s] = Up[(size_t)(tn + s) * (BB * HH)];

#pragma unroll
    for (int s = 0; s < 8; ++s) {
      const int t = tc + s;

      // Top barrier: h_t cross-wave writes visible. Pre-issued MFMAs from
      // the previous iteration drain in the matrix pipe during the wait.
      asm volatile("s_waitcnt lgkmcnt(0)\n\ts_barrier" ::: "memory");

      // ---- 6 cross-wave chunks of h_t (broadcast b128 reads) ----
      const _Float16* hb = hbuf[t & 1];
      half8_t h2 = *(const half8_t*)(hb + oX2);
      half8_t h3 = *(const half8_t*)(hb + oX3);
      half8_t h4 = *(const half8_t*)(hb + oX4);
      half8_t h5 = *(const half8_t*)(hb + oX5);
      half8_t h6 = *(const half8_t*)(hb + oX6);
      half8_t h7 = *(const half8_t*)(hb + oX7);
      asm volatile("" : "+v"(h2), "+v"(h3), "+v"(h4), "+v"(h5), "+v"(h6), "+v"(h7));

      // ---- 24 MFMAs completing step t (4 chains, chunk-major) ----
#pragma unroll
      for (int tt = 0; tt < 4; ++tt)
        cacc[tt] = __builtin_amdgcn_mfma_f32_16x16x32_f16(h2, wb[tt][2], cacc[tt], 0, 0, 0);
#pragma unroll
      for (int tt = 0; tt < 4; ++tt)
        cacc[tt] = __builtin_amdgcn_mfma_f32_16x16x32_f16(h3, wb[tt][3], cacc[tt], 0, 0, 0);
#pragma unroll
      for (int tt = 0; tt < 4; ++tt)
        cacc[tt] = __builtin_amdgcn_mfma_f32_16x16x32_f16(h4, wb[tt][4], cacc[tt], 0, 0, 0);
#pragma unroll
      for (int tt = 0; tt < 4; ++tt)
        cacc[tt] = __builtin_amdgcn_mfma_f32_16x16x32_f16(h5, wb[tt][5], cacc[tt], 0, 0, 0);
#pragma unroll
      for (int tt = 0; tt < 4; ++tt)
        cacc[tt] = __builtin_amdgcn_mfma_f32_16x16x32_f16(h6, wb[tt][6], cacc[tt], 0, 0, 0);
#pragma unroll
      for (int tt = 0; tt < 4; ++tt)
        cacc[tt] = __builtin_amdgcn_mfma_f32_16x16x32_f16(h7, wb[tt][7], cacc[tt], 0, 0, 0);

      // ---- finalize: quad q owns tile q  =>  n = 64w + 16q + col = tid ----
      float y = cacc[0][0];
      y = (quad == 1) ? cacc[1][0] : y;
      y = (quad == 2) ? cacc[2][0] : y;
      y = (quad == 3) ? cacc[3][0] : y;

      const float a = (float)uc[s] + y;
      // tanh(a) = 1 - 2/(exp(2a)+1)
      const float e = __builtin_amdgcn_exp2f(a * 2.885390081777927f);  // 2*log2(e)
      hn = 1.f - 2.f * __builtin_amdgcn_rcpf(e + 1.f);

      // ---- write own h_{t+1}, read own chunks, pre-issue 8 MFMAs (t+1) ----
      _Float16* hb1 = (_Float16*)hbuf[(t + 1) & 1];
      hb1[tid] = (_Float16)hn;
      half8_t hoA = *(const half8_t*)(hb1 + oO0);
      half8_t hoB = *(const half8_t*)(hb1 + oO1);
      asm volatile("" : "+v"(hoA), "+v"(hoB));
#pragma unroll
      for (int tt = 0; tt < 4; ++tt) cacc[tt] = (f32x4){0.f, 0.f, 0.f, 0.f};
#pragma unroll
      for (int tt = 0; tt < 4; ++tt)
        cacc[tt] = __builtin_amdgcn_mfma_f32_16x16x32_f16(hoA, wb[tt][0], cacc[tt], 0, 0, 0);
#pragma unroll
      for (int tt = 0; tt < 4; ++tt)
        cacc[tt] = __builtin_amdgcn_mfma_f32_16x16x32_f16(hoB, wb[tt][1], cacc[tt], 0, 0, 0);
      // loop wraps to lgkmcnt(0)+barrier; the 8 MFMAs drain across it.
    }
#pragma unroll
    for (int s = 0; s < 8; ++s) uc[s] = un[s];
  }
  out[(size_t)b * HH + tid] = hn;
}

// ---------------------------------------------------------------------------
extern "C" void kernel_launch(void* const* d_in, const int* in_sizes, int n_in,
                              void* d_out, int out_size, void* d_ws, size_t ws_size,
                              hipStream_t stream) {
  const int*   source = (const int*)d_in[0];
  const float* emb    = (const float*)d_in[1];
  const float* Wih    = (const float*)d_in[2];
  const float* Whh    = (const float*)d_in[3];
  const float* bih    = (const float*)d_in[4];
  const float* bhh    = (const float*)d_in[5];
  float* out = (float*)d_out;

  char* ws = (char*)d_ws;
  _Float16* U    = (_Float16*)ws;                    // 2048*64*256*2 = 67,108,864 B
  _Float16* WihT = (_Float16*)(ws + 67108864);       // 131,072 B
  _Float16* WhhT = (_Float16*)(ws + 67239936);       // 131,072 B
  int* done = (int*)(ws + 67371008);                 // TT ints
  int* wmp  = done + TT;                             // 1 int (total ~67.4 MB)

  hipMemsetAsync(done, 0, (TT + 1) * sizeof(int), stream);  // re-zero per replay
  prep_kernel<<<dim3(256), dim3(256), 0, stream>>>(Wih, Whh, WihT, WhhT);
  fused_kernel<<<dim3(BB + 4 * TT), dim3(256), 0, stream>>>(
      source, emb, WihT, WhhT, bih, bhh, U, out, done, wmp);
}

// Round 12
// 11242.713 us; speedup vs baseline: 1.0591x; 1.0591x over previous
//
#include <hip/hip_runtime.h>

#define TT 2048
#define BB 64
#define HH 256   // EMB == HID == 256

typedef _Float16 half8_t __attribute__((ext_vector_type(8)));
typedef float f32x4 __attribute__((ext_vector_type(4)));

// ---------------------------------------------------------------------------
// prep: transpose + fp16-convert W_ih and W_hh into [N][K] row-major. (~3 µs)
// ---------------------------------------------------------------------------
__global__ void prep_kernel(const float* __restrict__ Wih, const float* __restrict__ Whh,
                            _Float16* __restrict__ WihT, _Float16* __restrict__ WhhT) {
  const int n = blockIdx.x;   // output column
  const int k = threadIdx.x;  // input row
  WihT[n * HH + k] = (_Float16)Wih[k * HH + n];
  WhhT[n * HH + k] = (_Float16)Whh[k * HH + n];
}

// ---------------------------------------------------------------------------
// R21: fused producer/consumer, pathologies fixed.
//   R20 post-mortem: protocol CORRECT (absmax exact) but (a) 256-thread gate
//   = 64 serialized same-address agent-acquire atomics per poll per wave ->
//   L2 storm starved embed (HBM 30 GB/s, 12 ms); (b) 8192 one-shot embed
//   blocks at 1 block/CU: latency-bound gathers, Bs re-staged 8192x.
//   Fixes: tid0-only gate + __syncthreads broadcast (chunk top: vm/lgkm
//   queues empty -> drain free); 192 PERSISTENT embed blocks (grid=256,
//   one block/CU): block (g=e&3, p=e>>2) stages Bs once, loops t=p,p+48,...
//   ascending -> wm advances ~48 t / ~4 µs >> scan's 2.7 t/µs need.
//   Scan = frozen R15 body; embed = R9-verified fp32 body (absmax exact).
// ---------------------------------------------------------------------------
__global__ __launch_bounds__(256)
__attribute__((amdgpu_waves_per_eu(1, 1)))
void fused_kernel(const int* __restrict__ source, const float* __restrict__ emb,
                  const _Float16* __restrict__ WihT, const _Float16* __restrict__ WhhT,
                  const float* __restrict__ b_ih, const float* __restrict__ b_hh,
                  _Float16* __restrict__ U, float* __restrict__ out,
                  int* __restrict__ done, int* __restrict__ wmp) {
  __shared__ __align__(16) _Float16 Bs[64][280];   // embed role (36 KB)
  __shared__ __align__(16) _Float16 hbuf[2][HH];   // scan role (1 KB)
  const int tid = threadIdx.x;

  if (blockIdx.x >= BB) {
    // ============ embed role: persistent, R9-verified body ============
    const int e = blockIdx.x - BB;   // 0..191
    const int nbase = (e & 3) * 64;  // ngroup
    const int p = e >> 2;            // 0..47: t = p, p+48, ...

    for (int c = tid; c < 64 * 32; c += 256) {
      const int n = c >> 5;
      const int ko = (c & 31) * 8;
      *(half8_t*)&Bs[n][ko] = *(const half8_t*)(WihT + (size_t)(nbase + n) * HH + ko);
    }
    __syncthreads();

    const int lane = tid & 63;
    const int wave = tid >> 6;
    const int row16 = lane & 15;
    const int quad = lane >> 4;
    const int b = wave * 16 + row16;            // A-fragment row = batch

    float bias[4];
#pragma unroll
    for (int ct = 0; ct < 4; ++ct) {
      const int nn = nbase + ct * 16 + row16;
      bias[ct] = b_ih[nn] + b_hh[nn];
    }

    for (int t = p; t < TT; t += 48) {
      const int src = source[b * TT + t];       // source is [B][T]
      const float* arow = emb + (size_t)src * HH + quad * 8;

      f32x4 acc[4];
#pragma unroll
      for (int ct = 0; ct < 4; ++ct) acc[ct] = (f32x4){0.f, 0.f, 0.f, 0.f};

#pragma unroll
      for (int kt = 0; kt < 8; ++kt) {
        const float4 x0 = *(const float4*)(arow + kt * 32);
        const float4 x1 = *(const float4*)(arow + kt * 32 + 4);
        half8_t af;
        af[0] = (_Float16)x0.x; af[1] = (_Float16)x0.y;
        af[2] = (_Float16)x0.z; af[3] = (_Float16)x0.w;
        af[4] = (_Float16)x1.x; af[5] = (_Float16)x1.y;
        af[6] = (_Float16)x1.z; af[7] = (_Float16)x1.w;
#pragma unroll
        for (int ct = 0; ct < 4; ++ct) {
          const half8_t bf = *(const half8_t*)&Bs[ct * 16 + row16][quad * 8 + kt * 32];
          acc[ct] = __builtin_amdgcn_mfma_f32_16x16x32_f16(af, bf, acc[ct], 0, 0, 0);
        }
      }

#pragma unroll
      for (int ct = 0; ct < 4; ++ct) {
        const int nn = nbase + ct * 16 + row16; // C col = lane&15
#pragma unroll
        for (int r = 0; r < 4; ++r) {
          const int bb = wave * 16 + quad * 4 + r;  // C row = quad*4 + reg
          U[((size_t)t * BB + bb) * HH + nn] = (_Float16)(acc[ct][r] + bias[ct]);
        }
      }

      // ---- publish t: stores -> fence -> block barrier -> tid0 signal ----
      __threadfence();
      __syncthreads();
      if (tid == 0) {
        __hip_atomic_fetch_add(&done[t], 1, __ATOMIC_RELEASE, __HIP_MEMORY_SCOPE_AGENT);
        int w = __hip_atomic_load(wmp, __ATOMIC_RELAXED, __HIP_MEMORY_SCOPE_AGENT);
        while (w < TT &&
               __hip_atomic_load(&done[w], __ATOMIC_ACQUIRE, __HIP_MEMORY_SCOPE_AGENT) == 4) {
          int expct = w;
          if (__hip_atomic_compare_exchange_strong(wmp, &expct, w + 1, __ATOMIC_RELEASE,
                                                   __ATOMIC_RELAXED, __HIP_MEMORY_SCOPE_AGENT))
            w = w + 1;
          else
            w = expct;
        }
      }
      __syncthreads();  // keep waves together before next t
    }
    return;
  }

  // ================= scan role (R15 body, FROZEN math) =================
  const int b = blockIdx.x;
  const int w = tid >> 6;
  const int l = tid & 63;
  const int col = l & 15;    // n within tile
  const int quad = l >> 4;   // MFMA quad

  half8_t wb[4][8];
#pragma unroll
  for (int tt = 0; tt < 4; ++tt) {
    const _Float16* base = WhhT + (size_t)(64 * w + 16 * tt + col) * HH + quad * 8;
#pragma unroll
    for (int j = 0; j < 8; ++j) {
      const int c = (2 * w + j) & 7;
      wb[tt][j] = *(const half8_t*)(base + 32 * c);
    }
  }
  asm volatile("" : "+a"(wb[0][0]), "+a"(wb[0][1]), "+a"(wb[0][2]), "+a"(wb[0][3]),
                    "+a"(wb[0][4]), "+a"(wb[0][5]), "+a"(wb[0][6]), "+a"(wb[0][7]),
                    "+a"(wb[1][0]), "+a"(wb[1][1]), "+a"(wb[1][2]), "+a"(wb[1][3]),
                    "+a"(wb[1][4]), "+a"(wb[1][5]), "+a"(wb[1][6]), "+a"(wb[1][7]));
  asm volatile("" : "+a"(wb[2][0]), "+a"(wb[2][1]), "+a"(wb[2][2]), "+a"(wb[2][3]),
                    "+a"(wb[2][4]), "+a"(wb[2][5]), "+a"(wb[2][6]), "+a"(wb[2][7]),
                    "+a"(wb[3][0]), "+a"(wb[3][1]), "+a"(wb[3][2]), "+a"(wb[3][3]),
                    "+a"(wb[3][4]), "+a"(wb[3][5]), "+a"(wb[3][6]), "+a"(wb[3][7]));

  const int oO0 = 32 * ((2 * w + 0) & 7) + 8 * quad;  // own chunk j=0
  const int oO1 = 32 * ((2 * w + 1) & 7) + 8 * quad;  // own chunk j=1
  const int oX2 = 32 * ((2 * w + 2) & 7) + 8 * quad;
  const int oX3 = 32 * ((2 * w + 3) & 7) + 8 * quad;
  const int oX4 = 32 * ((2 * w + 4) & 7) + 8 * quad;
  const int oX5 = 32 * ((2 * w + 5) & 7) + 8 * quad;
  const int oX6 = 32 * ((2 * w + 6) & 7) + 8 * quad;
  const int oX7 = 32 * ((2 * w + 7) & 7) + 8 * quad;

  hbuf[0][tid] = (_Float16)0.f;  // h0 = 0

  // tid0-only producer gate; __syncthreads broadcasts (chunk top: vm/lgkm
  // queues are empty there, so the implicit drain is free).
  int ready0 = 0;
  long spin_budget = 1L << 24;
  auto gate = [&](int need) {
    if (tid == 0) {
      while (ready0 < need) {
        ready0 = __hip_atomic_load(wmp, __ATOMIC_ACQUIRE, __HIP_MEMORY_SCOPE_AGENT);
        if (ready0 >= need || --spin_budget < 0) break;
        __builtin_amdgcn_s_sleep(16);
      }
    }
    __syncthreads();
  };

  const _Float16* Up = U + b * HH + tid;  // step stride = BB*HH halfs
  _Float16 uc[8], un[8];
  gate(8);
#pragma unroll
  for (int s = 0; s < 8; ++s) uc[s] = Up[(size_t)s * (BB * HH)];

  float hn = 0.f;
  f32x4 cacc[4];
#pragma unroll
  for (int tt = 0; tt < 4; ++tt) cacc[tt] = (f32x4){0.f, 0.f, 0.f, 0.f};

  // ---- prologue: own-chunk frags of h_0 + 8 pre-issued MFMAs (step 0) ----
  {
    half8_t hoA = *(const half8_t*)(hbuf[0] + oO0);
    half8_t hoB = *(const half8_t*)(hbuf[0] + oO1);
    asm volatile("" : "+v"(hoA), "+v"(hoB));
#pragma unroll
    for (int tt = 0; tt < 4; ++tt)
      cacc[tt] = __builtin_amdgcn_mfma_f32_16x16x32_f16(hoA, wb[tt][0], cacc[tt], 0, 0, 0);
#pragma unroll
    for (int tt = 0; tt < 4; ++tt)
      cacc[tt] = __builtin_amdgcn_mfma_f32_16x16x32_f16(hoB, wb[tt][1], cacc[tt], 0, 0, 0);
  }

  for (int tc = 0; tc < TT; tc += 8) {
    // Gate next-chunk availability, then issue u-loads; raw barriers never
    // drain vmcnt, so they stay in flight 8 steps.
    const int tn = (tc + 8) & (TT - 1);
    gate((tc + 16 < TT) ? (tc + 16) : TT);
#pragma unroll
    for (int s = 0; s < 8; ++s) un[s] = Up[(size_t)(tn + s) * (BB * HH)];

#pragma unroll
    for (int s = 0; s < 8; ++s) {
      const int t = tc + s;

      asm volatile("s_waitcnt lgkmcnt(0)\n\ts_barrier" ::: "memory");

      const _Float16* hb = hbuf[t & 1];
      half8_t h2 = *(const half8_t*)(hb + oX2);
      half8_t h3 = *(const half8_t*)(hb + oX3);
      half8_t h4 = *(const half8_t*)(hb + oX4);
      half8_t h5 = *(const half8_t*)(hb + oX5);
      half8_t h6 = *(const half8_t*)(hb + oX6);
      half8_t h7 = *(const half8_t*)(hb + oX7);
      asm volatile("" : "+v"(h2), "+v"(h3), "+v"(h4), "+v"(h5), "+v"(h6), "+v"(h7));

#pragma unroll
      for (int tt = 0; tt < 4; ++tt)
        cacc[tt] = __builtin_amdgcn_mfma_f32_16x16x32_f16(h2, wb[tt][2], cacc[tt], 0, 0, 0);
#pragma unroll
      for (int tt = 0; tt < 4; ++tt)
        cacc[tt] = __builtin_amdgcn_mfma_f32_16x16x32_f16(h3, wb[tt][3], cacc[tt], 0, 0, 0);
#pragma unroll
      for (int tt = 0; tt < 4; ++tt)
        cacc[tt] = __builtin_amdgcn_mfma_f32_16x16x32_f16(h4, wb[tt][4], cacc[tt], 0, 0, 0);
#pragma unroll
      for (int tt = 0; tt < 4; ++tt)
        cacc[tt] = __builtin_amdgcn_mfma_f32_16x16x32_f16(h5, wb[tt][5], cacc[tt], 0, 0, 0);
#pragma unroll
      for (int tt = 0; tt < 4; ++tt)
        cacc[tt] = __builtin_amdgcn_mfma_f32_16x16x32_f16(h6, wb[tt][6], cacc[tt], 0, 0, 0);
#pragma unroll
      for (int tt = 0; tt < 4; ++tt)
        cacc[tt] = __builtin_amdgcn_mfma_f32_16x16x32_f16(h7, wb[tt][7], cacc[tt], 0, 0, 0);

      float y = cacc[0][0];
      y = (quad == 1) ? cacc[1][0] : y;
      y = (quad == 2) ? cacc[2][0] : y;
      y = (quad == 3) ? cacc[3][0] : y;

      const float a = (float)uc[s] + y;
      const float e = __builtin_amdgcn_exp2f(a * 2.885390081777927f);  // 2*log2(e)
      hn = 1.f - 2.f * __builtin_amdgcn_rcpf(e + 1.f);

      _Float16* hb1 = (_Float16*)hbuf[(t + 1) & 1];
      hb1[tid] = (_Float16)hn;
      half8_t hoA = *(const half8_t*)(hb1 + oO0);
      half8_t hoB = *(const half8_t*)(hb1 + oO1);
      asm volatile("" : "+v"(hoA), "+v"(hoB));
#pragma unroll
      for (int tt = 0; tt < 4; ++tt) cacc[tt] = (f32x4){0.f, 0.f, 0.f, 0.f};
#pragma unroll
      for (int tt = 0; tt < 4; ++tt)
        cacc[tt] = __builtin_amdgcn_mfma_f32_16x16x32_f16(hoA, wb[tt][0], cacc[tt], 0, 0, 0);
#pragma unroll
      for (int tt = 0; tt < 4; ++tt)
        cacc[tt] = __builtin_amdgcn_mfma_f32_16x16x32_f16(hoB, wb[tt][1], cacc[tt], 0, 0, 0);
    }
#pragma unroll
    for (int s = 0; s < 8; ++s) uc[s] = un[s];
  }
  out[(size_t)b * HH + tid] = hn;
}

// ---------------------------------------------------------------------------
extern "C" void kernel_launch(void* const* d_in, const int* in_sizes, int n_in,
                              void* d_out, int out_size, void* d_ws, size_t ws_size,
                              hipStream_t stream) {
  const int*   source = (const int*)d_in[0];
  const float* emb    = (const float*)d_in[1];
  const float* Wih    = (const float*)d_in[2];
  const float* Whh    = (const float*)d_in[3];
  const float* bih    = (const float*)d_in[4];
  const float* bhh    = (const float*)d_in[5];
  float* out = (float*)d_out;

  char* ws = (char*)d_ws;
  _Float16* U    = (_Float16*)ws;                    // 2048*64*256*2 = 67,108,864 B
  _Float16* WihT = (_Float16*)(ws + 67108864);       // 131,072 B
  _Float16* WhhT = (_Float16*)(ws + 67239936);       // 131,072 B
  int* done = (int*)(ws + 67371008);                 // TT ints
  int* wmp  = done + TT;                             // 1 int

  hipMemsetAsync(done, 0, (TT + 1) * sizeof(int), stream);  // re-zero per replay
  prep_kernel<<<dim3(256), dim3(256), 0, stream>>>(Wih, Whh, WihT, WhhT);
  fused_kernel<<<dim3(256), dim3(256), 0, stream>>>(
      source, emb, WihT, WhhT, bih, bhh, U, out, done, wmp);
}

// Round 13
// 876.117 us; speedup vs baseline: 13.5911x; 12.8324x over previous
//
#include <hip/hip_runtime.h>

#define TT 2048
#define BB 64
#define HH 256   // EMB == HID == 256
#define TPB 4    // t-values per embed block (R17-proven best of three)

typedef _Float16 half2_t __attribute__((ext_vector_type(2)));
typedef _Float16 half8_t __attribute__((ext_vector_type(8)));
typedef float f32x4 __attribute__((ext_vector_type(4)));

// ---------------------------------------------------------------------------
// prep: transpose + fp16-convert W_ih/W_hh; fp16-convert emb table.
// Blocks 0..255 do the transposes; all blocks grid-stride the emb convert.
// ---------------------------------------------------------------------------
__global__ void prep_kernel(const float* __restrict__ Wih, const float* __restrict__ Whh,
                            _Float16* __restrict__ WihT, _Float16* __restrict__ WhhT,
                            const float* __restrict__ emb, _Float16* __restrict__ emb16,
                            int do_emb) {
  if (blockIdx.x < 256) {
    const int n = blockIdx.x;   // output column
    const int k = threadIdx.x;  // input row
    WihT[n * HH + k] = (_Float16)Wih[k * HH + n];
    WhhT[n * HH + k] = (_Float16)Whh[k * HH + n];
  }
  if (do_emb) {
    const long nchunk = 32000L * HH / 8;  // half8 chunks
    for (long i = (long)blockIdx.x * blockDim.x + threadIdx.x; i < nchunk;
         i += (long)gridDim.x * blockDim.x) {
      const float4 x0 = *(const float4*)(emb + 8 * i);
      const float4 x1 = *(const float4*)(emb + 8 * i + 4);
      half8_t h;
      h[0] = (_Float16)x0.x; h[1] = (_Float16)x0.y;
      h[2] = (_Float16)x0.z; h[3] = (_Float16)x0.w;
      h[4] = (_Float16)x1.x; h[5] = (_Float16)x1.y;
      h[6] = (_Float16)x1.z; h[7] = (_Float16)x1.w;
      *(half8_t*)(emb16 + 8 * i) = h;
    }
  }
}

// ---------------------------------------------------------------------------
// Part A (R17 config — best measured of all embed variants: 876 µs total).
//   fp16 emb table (halves gather bytes, kills 64 cvt/lane) + TPB=4
//   t-values per block. fp32->fp16 rounding identical to in-kernel cvt =>
//   absmax repeats exactly.
//   R20/R21 post-mortem (fusion attempts, both 12 ms): in-kernel producer->
//   consumer across XCDs requires agent-scope release fences = full per-XCD
//   L2 writebacks per tile + acquire-poll L2 invalidates on the consumer —
//   FETCH inflated 2x, HBM throttled to 29 GB/s. Structurally unprofitable
//   on gfx950 (Guideline 16). Serial prep -> embed -> scan is the right
//   shape; this file is the best measured configuration.
// ---------------------------------------------------------------------------
__global__ __launch_bounds__(256, 2) void embed_gemm16_kernel(
    const int* __restrict__ source, const _Float16* __restrict__ emb16,
    const _Float16* __restrict__ WihT, const float* __restrict__ b_ih,
    const float* __restrict__ b_hh, _Float16* __restrict__ U) {
  const int t0 = blockIdx.x * TPB;
  const int nbase = blockIdx.y * 64;
  __shared__ __align__(16) _Float16 Bs[64][280];

  const int tid = threadIdx.x;
  for (int c = tid; c < 64 * 32; c += 256) {
    const int n = c >> 5;
    const int ko = (c & 31) * 8;
    *(half8_t*)&Bs[n][ko] = *(const half8_t*)(WihT + (size_t)(nbase + n) * HH + ko);
  }
  __syncthreads();

  const int lane = tid & 63;
  const int wave = tid >> 6;
  const int row16 = lane & 15;
  const int quad = lane >> 4;
  const int b = wave * 16 + row16;              // A-fragment row = batch

  // bias per n-tile (hoisted out of the t loop)
  float bias[4];
#pragma unroll
  for (int ct = 0; ct < 4; ++ct) {
    const int nn = nbase + ct * 16 + row16;
    bias[ct] = b_ih[nn] + b_hh[nn];
  }

  for (int ts = 0; ts < TPB; ++ts) {
    const int t = t0 + ts;
    const int src = source[b * TT + t];         // source is [B][T]
    const _Float16* arow = emb16 + (size_t)src * HH + quad * 8;

    f32x4 acc[4];
#pragma unroll
    for (int ct = 0; ct < 4; ++ct) acc[ct] = (f32x4){0.f, 0.f, 0.f, 0.f};

#pragma unroll
    for (int kt = 0; kt < 8; ++kt) {
      const half8_t af = *(const half8_t*)(arow + kt * 32);
#pragma unroll
      for (int ct = 0; ct < 4; ++ct) {
        const half8_t bf = *(const half8_t*)&Bs[ct * 16 + row16][quad * 8 + kt * 32];
        acc[ct] = __builtin_amdgcn_mfma_f32_16x16x32_f16(af, bf, acc[ct], 0, 0, 0);
      }
    }

#pragma unroll
    for (int ct = 0; ct < 4; ++ct) {
      const int nn = nbase + ct * 16 + row16;   // C col = lane&15
#pragma unroll
      for (int r = 0; r < 4; ++r) {
        const int bb = wave * 16 + quad * 4 + r;  // C row = quad*4 + reg
        U[((size_t)t * BB + bb) * HH + nn] = (_Float16)(acc[ct][r] + bias[ct]);
      }
    }
  }
}

// ---------------------------------------------------------------------------
// Part A (fallback, original): used only if ws_size can't hold emb16.
// ---------------------------------------------------------------------------
__global__ __launch_bounds__(256, 2) void embed_gemm_kernel(
    const int* __restrict__ source, const float* __restrict__ emb,
    const _Float16* __restrict__ WihT, const float* __restrict__ b_ih,
    const float* __restrict__ b_hh, _Float16* __restrict__ U) {
  const int t = blockIdx.x;
  const int nbase = blockIdx.y * 64;
  __shared__ __align__(16) _Float16 Bs[64][280];

  const int tid = threadIdx.x;
  for (int c = tid; c < 64 * 32; c += 256) {
    const int n = c >> 5;
    const int ko = (c & 31) * 8;
    *(half8_t*)&Bs[n][ko] = *(const half8_t*)(WihT + (size_t)(nbase + n) * HH + ko);
  }
  __syncthreads();

  const int lane = tid & 63;
  const int wave = tid >> 6;
  const int row16 = lane & 15;
  const int quad = lane >> 4;
  const int b = wave * 16 + row16;
  const int src = source[b * TT + t];
  const float* arow = emb + (size_t)src * HH + quad * 8;

  f32x4 acc[4];
#pragma unroll
  for (int ct = 0; ct < 4; ++ct) acc[ct] = (f32x4){0.f, 0.f, 0.f, 0.f};

#pragma unroll
  for (int kt = 0; kt < 8; ++kt) {
    const float4 x0 = *(const float4*)(arow + kt * 32);
    const float4 x1 = *(const float4*)(arow + kt * 32 + 4);
    half8_t af;
    af[0] = (_Float16)x0.x; af[1] = (_Float16)x0.y;
    af[2] = (_Float16)x0.z; af[3] = (_Float16)x0.w;
    af[4] = (_Float16)x1.x; af[5] = (_Float16)x1.y;
    af[6] = (_Float16)x1.z; af[7] = (_Float16)x1.w;
#pragma unroll
    for (int ct = 0; ct < 4; ++ct) {
      const half8_t bf = *(const half8_t*)&Bs[ct * 16 + row16][quad * 8 + kt * 32];
      acc[ct] = __builtin_amdgcn_mfma_f32_16x16x32_f16(af, bf, acc[ct], 0, 0, 0);
    }
  }

#pragma unroll
  for (int ct = 0; ct < 4; ++ct) {
    const int nn = nbase + ct * 16 + row16;
    const float bias = b_ih[nn] + b_hh[nn];
#pragma unroll
    for (int r = 0; r < 4; ++r) {
      const int bb = wave * 16 + quad * 4 + r;
      U[((size_t)t * BB + bb) * HH + nn] = (_Float16)(acc[ct][r] + bias);
    }
  }
}

// ---------------------------------------------------------------------------
// Part B: recurrence — R15 structure, FROZEN (best measured: scan ~762 µs,
//   ~893 cy/step, ~4% above the modeled floor of this decomposition: 620 cy
//   per-SIMD MFMA issue [the CU matrix pipe is saturated during the MFMA
//   phase at the measured ~4.85 cy/MFMA full-chip rate] + drain + finalize/
//   tanh + LDS write->own-read + barrier). Alternatives all measured worse:
//   pure-VALU dot2 (allocator parks >~130 arch VGPRs, 3x), 8-wave splits
//   (DS-bound / lockstep), hybrid MFMA+dot (serial add), split chains +
//   kZero C-in (AGPR refill). Cross-CU N/K-splits need per-step agent-scope
//   exchange, which R20/R21 measured at ~ms (L2 writeback/invalidate per
//   handoff). Do not touch.
// ---------------------------------------------------------------------------
__global__ __launch_bounds__(256)
__attribute__((amdgpu_waves_per_eu(1, 1)))
void rnn_scan_kernel(
    const _Float16* __restrict__ U, const _Float16* __restrict__ WhhT,
    float* __restrict__ out) {
  const int b = blockIdx.x;
  const int tid = threadIdx.x;
  const int w = tid >> 6;
  const int l = tid & 63;
  const int col = l & 15;    // n within tile
  const int quad = l >> 4;   // MFMA quad

  __shared__ __align__(16) _Float16 hbuf[2][HH];  // 1 KB ping-pong

  // wb[tt][j]: B-frag for n-tile 64w+16tt, k-chunk c=(2w+j)&7 (own chunks at
  // j=0,1). Lane reads WhhT[(64w+16tt+col)][32c + quad*8 .. +8] (16B aligned).
  half8_t wb[4][8];
#pragma unroll
  for (int tt = 0; tt < 4; ++tt) {
    const _Float16* base = WhhT + (size_t)(64 * w + 16 * tt + col) * HH + quad * 8;
#pragma unroll
    for (int j = 0; j < 8; ++j) {
      const int c = (2 * w + j) & 7;
      wb[tt][j] = *(const half8_t*)(base + 32 * c);
    }
  }
  // Pin into AGPRs ("a"): one-time v_accvgpr_write; MFMA reads B from AGPR.
  asm volatile("" : "+a"(wb[0][0]), "+a"(wb[0][1]), "+a"(wb[0][2]), "+a"(wb[0][3]),
                    "+a"(wb[0][4]), "+a"(wb[0][5]), "+a"(wb[0][6]), "+a"(wb[0][7]),
                    "+a"(wb[1][0]), "+a"(wb[1][1]), "+a"(wb[1][2]), "+a"(wb[1][3]),
                    "+a"(wb[1][4]), "+a"(wb[1][5]), "+a"(wb[1][6]), "+a"(wb[1][7]));
  asm volatile("" : "+a"(wb[2][0]), "+a"(wb[2][1]), "+a"(wb[2][2]), "+a"(wb[2][3]),
                    "+a"(wb[2][4]), "+a"(wb[2][5]), "+a"(wb[2][6]), "+a"(wb[2][7]),
                    "+a"(wb[3][0]), "+a"(wb[3][1]), "+a"(wb[3][2]), "+a"(wb[3][3]),
                    "+a"(wb[3][4]), "+a"(wb[3][5]), "+a"(wb[3][6]), "+a"(wb[3][7]));

  // h-read offsets (halfs): chunk (2w+j)&7 at 32*c + 8*quad.
  const int oO0 = 32 * ((2 * w + 0) & 7) + 8 * quad;  // own chunk j=0
  const int oO1 = 32 * ((2 * w + 1) & 7) + 8 * quad;  // own chunk j=1
  const int oX2 = 32 * ((2 * w + 2) & 7) + 8 * quad;
  const int oX3 = 32 * ((2 * w + 3) & 7) + 8 * quad;
  const int oX4 = 32 * ((2 * w + 4) & 7) + 8 * quad;
  const int oX5 = 32 * ((2 * w + 5) & 7) + 8 * quad;
  const int oX6 = 32 * ((2 * w + 6) & 7) + 8 * quad;
  const int oX7 = 32 * ((2 * w + 7) & 7) + 8 * quad;

  hbuf[0][tid] = (_Float16)0.f;  // h0 = 0

  // Thread tid finalizes output n = tid: u stream is per-thread contiguous.
  const _Float16* Up = U + b * HH + tid;  // step stride = BB*HH halfs
  _Float16 uc[8], un[8];
#pragma unroll
  for (int s = 0; s < 8; ++s) uc[s] = Up[(size_t)s * (BB * HH)];

  float hn = 0.f;
  f32x4 cacc[4];
#pragma unroll
  for (int tt = 0; tt < 4; ++tt) cacc[tt] = (f32x4){0.f, 0.f, 0.f, 0.f};

  // ---- prologue: own-chunk frags of h_0 + 8 pre-issued MFMAs (step 0) ----
  {
    half8_t hoA = *(const half8_t*)(hbuf[0] + oO0);
    half8_t hoB = *(const half8_t*)(hbuf[0] + oO1);
    asm volatile("" : "+v"(hoA), "+v"(hoB));
#pragma unroll
    for (int tt = 0; tt < 4; ++tt)
      cacc[tt] = __builtin_amdgcn_mfma_f32_16x16x32_f16(hoA, wb[tt][0], cacc[tt], 0, 0, 0);
#pragma unroll
    for (int tt = 0; tt < 4; ++tt)
      cacc[tt] = __builtin_amdgcn_mfma_f32_16x16x32_f16(hoB, wb[tt][1], cacc[tt], 0, 0, 0);
  }

  for (int tc = 0; tc < TT; tc += 8) {
    // Issue all next-chunk u-loads; raw barriers never drain vmcnt, so they
    // stay in flight until the uc=un copy (8 steps of slack).
    const int tn = (tc + 8) & (TT - 1);
#pragma unroll
    for (int s = 0; s < 8; ++s) un[s] = Up[(size_t)(tn + s) * (BB * HH)];

#pragma unroll
    for (int s = 0; s < 8; ++s) {
      const int t = tc + s;

      // Top barrier: h_t cross-wave writes visible. Pre-issued MFMAs from
      // the previous iteration drain in the matrix pipe during the wait.
      asm volatile("s_waitcnt lgkmcnt(0)\n\ts_barrier" ::: "memory");

      // ---- 6 cross-wave chunks of h_t (broadcast b128 reads) ----
      const _Float16* hb = hbuf[t & 1];
      half8_t h2 = *(const half8_t*)(hb + oX2);
      half8_t h3 = *(const half8_t*)(hb + oX3);
      half8_t h4 = *(const half8_t*)(hb + oX4);
      half8_t h5 = *(const half8_t*)(hb + oX5);
      half8_t h6 = *(const half8_t*)(hb + oX6);
      half8_t h7 = *(const half8_t*)(hb + oX7);
      asm volatile("" : "+v"(h2), "+v"(h3), "+v"(h4), "+v"(h5), "+v"(h6), "+v"(h7));

      // ---- 24 MFMAs completing step t (4 chains, chunk-major) ----
#pragma unroll
      for (int tt = 0; tt < 4; ++tt)
        cacc[tt] = __builtin_amdgcn_mfma_f32_16x16x32_f16(h2, wb[tt][2], cacc[tt], 0, 0, 0);
#pragma unroll
      for (int tt = 0; tt < 4; ++tt)
        cacc[tt] = __builtin_amdgcn_mfma_f32_16x16x32_f16(h3, wb[tt][3], cacc[tt], 0, 0, 0);
#pragma unroll
      for (int tt = 0; tt < 4; ++tt)
        cacc[tt] = __builtin_amdgcn_mfma_f32_16x16x32_f16(h4, wb[tt][4], cacc[tt], 0, 0, 0);
#pragma unroll
      for (int tt = 0; tt < 4; ++tt)
        cacc[tt] = __builtin_amdgcn_mfma_f32_16x16x32_f16(h5, wb[tt][5], cacc[tt], 0, 0, 0);
#pragma unroll
      for (int tt = 0; tt < 4; ++tt)
        cacc[tt] = __builtin_amdgcn_mfma_f32_16x16x32_f16(h6, wb[tt][6], cacc[tt], 0, 0, 0);
#pragma unroll
      for (int tt = 0; tt < 4; ++tt)
        cacc[tt] = __builtin_amdgcn_mfma_f32_16x16x32_f16(h7, wb[tt][7], cacc[tt], 0, 0, 0);

      // ---- finalize: quad q owns tile q  =>  n = 64w + 16q + col = tid ----
      float y = cacc[0][0];
      y = (quad == 1) ? cacc[1][0] : y;
      y = (quad == 2) ? cacc[2][0] : y;
      y = (quad == 3) ? cacc[3][0] : y;

      const float a = (float)uc[s] + y;
      // tanh(a) = 1 - 2/(exp(2a)+1)
      const float e = __builtin_amdgcn_exp2f(a * 2.885390081777927f);  // 2*log2(e)
      hn = 1.f - 2.f * __builtin_amdgcn_rcpf(e + 1.f);

      // ---- write own h_{t+1}, read own chunks, pre-issue 8 MFMAs (t+1) ----
      _Float16* hb1 = (_Float16*)hbuf[(t + 1) & 1];
      hb1[tid] = (_Float16)hn;
      // Same-wave DS ordering: these reads see the wave's own writes above.
      half8_t hoA = *(const half8_t*)(hb1 + oO0);
      half8_t hoB = *(const half8_t*)(hb1 + oO1);
      asm volatile("" : "+v"(hoA), "+v"(hoB));
#pragma unroll
      for (int tt = 0; tt < 4; ++tt) cacc[tt] = (f32x4){0.f, 0.f, 0.f, 0.f};
#pragma unroll
      for (int tt = 0; tt < 4; ++tt)
        cacc[tt] = __builtin_amdgcn_mfma_f32_16x16x32_f16(hoA, wb[tt][0], cacc[tt], 0, 0, 0);
#pragma unroll
      for (int tt = 0; tt < 4; ++tt)
        cacc[tt] = __builtin_amdgcn_mfma_f32_16x16x32_f16(hoB, wb[tt][1], cacc[tt], 0, 0, 0);
      // loop wraps to lgkmcnt(0)+barrier; the 8 MFMAs drain across it.
    }
#pragma unroll
    for (int s = 0; s < 8; ++s) uc[s] = un[s];
  }
  out[(size_t)b * HH + tid] = hn;
}

// ---------------------------------------------------------------------------
extern "C" void kernel_launch(void* const* d_in, const int* in_sizes, int n_in,
                              void* d_out, int out_size, void* d_ws, size_t ws_size,
                              hipStream_t stream) {
  const int*   source = (const int*)d_in[0];
  const float* emb    = (const float*)d_in[1];
  const float* Wih    = (const float*)d_in[2];
  const float* Whh    = (const float*)d_in[3];
  const float* bih    = (const float*)d_in[4];
  const float* bhh    = (const float*)d_in[5];
  float* out = (float*)d_out;

  char* ws = (char*)d_ws;
  _Float16* U     = (_Float16*)ws;                    // 2048*64*256*2 = 67,108,864 B
  _Float16* WihT  = (_Float16*)(ws + 67108864);       // 131,072 B
  _Float16* WhhT  = (_Float16*)(ws + 67239936);       // 131,072 B
  _Float16* emb16 = (_Float16*)(ws + 67371008);       // 32000*256*2 = 16,384,000 B
  const size_t need16 = 67371008u + 16384000u;        // 83,755,008 B

  if (ws_size >= need16) {
    prep_kernel<<<dim3(2048), dim3(256), 0, stream>>>(Wih, Whh, WihT, WhhT, emb, emb16, 1);
    embed_gemm16_kernel<<<dim3(TT / TPB, 4), dim3(256), 0, stream>>>(source, emb16, WihT, bih, bhh, U);
  } else {
    prep_kernel<<<dim3(256), dim3(256), 0, stream>>>(Wih, Whh, WihT, WhhT, emb, (_Float16*)WihT, 0);
    embed_gemm_kernel<<<dim3(TT, 4), dim3(256), 0, stream>>>(source, emb, WihT, bih, bhh, U);
  }
  rnn_scan_kernel<<<dim3(BB), dim3(256), 0, stream>>>(U, WhhT, out);
}